// Round 1
// baseline (115.396 us; speedup 1.0000x reference)
//
#include <hip/hip_runtime.h>

#define NC 20            // classes (compile-time; in_sizes[0]/in_sizes[1] == 20)
#define NP 100           // probes
#define TEMP 10.0f
#define CHUNK 2048

// Order-preserving float <-> uint key (for atomic min/max on floats)
__device__ __forceinline__ unsigned enc_f(float f) {
    unsigned u = __float_as_uint(f);
    return (u & 0x80000000u) ? ~u : (u | 0x80000000u);
}
__device__ __forceinline__ float dec_f(unsigned k) {
    unsigned u = (k & 0x80000000u) ? (k & 0x7fffffffu) : ~k;
    return __uint_as_float(u);
}

// Kernel 1: per-class min/max + count of s==1
__global__ __launch_bounds__(256)
void minmax_kernel(const float* __restrict__ y, const int* __restrict__ s,
                   unsigned* __restrict__ mnk, unsigned* __restrict__ mxk,
                   int* __restrict__ n1cnt, int N) {
    float mn[NC], mx[NC];
#pragma unroll
    for (int c = 0; c < NC; ++c) { mn[c] = 3.4e38f; mx[c] = -3.4e38f; }
    int cnt = 0;
    int stride = gridDim.x * blockDim.x;
    for (int n = blockIdx.x * blockDim.x + threadIdx.x; n < N; n += stride) {
        const float4* row = (const float4*)(y + (size_t)n * NC);
#pragma unroll
        for (int q = 0; q < NC / 4; ++q) {
            float4 v = row[q];
            mn[4*q+0] = fminf(mn[4*q+0], v.x); mx[4*q+0] = fmaxf(mx[4*q+0], v.x);
            mn[4*q+1] = fminf(mn[4*q+1], v.y); mx[4*q+1] = fmaxf(mx[4*q+1], v.y);
            mn[4*q+2] = fminf(mn[4*q+2], v.z); mx[4*q+2] = fmaxf(mx[4*q+2], v.z);
            mn[4*q+3] = fminf(mn[4*q+3], v.w); mx[4*q+3] = fmaxf(mx[4*q+3], v.w);
        }
        cnt += s[n];
    }
    // wave-level reduce (64 lanes)
#pragma unroll
    for (int off = 1; off < 64; off <<= 1) {
#pragma unroll
        for (int c = 0; c < NC; ++c) {
            mn[c] = fminf(mn[c], __shfl_xor(mn[c], off));
            mx[c] = fmaxf(mx[c], __shfl_xor(mx[c], off));
        }
        cnt += __shfl_xor(cnt, off);
    }
    if ((threadIdx.x & 63) == 0) {
#pragma unroll
        for (int c = 0; c < NC; ++c) {
            atomicMin(&mnk[c], enc_f(mn[c]));
            atomicMax(&mxk[c], enc_f(mx[c]));
        }
        atomicAdd(n1cnt, cnt);
    }
}

// Kernel 2: block = (class c, n-chunk k). Stage preds*10 + mask in LDS,
// each wave owns probes p = wave, wave+4, ...; accumulate tot & group1 sums.
__global__ __launch_bounds__(256)
void cdf_kernel(const float* __restrict__ y, const int* __restrict__ s,
                const unsigned* __restrict__ mnk, const unsigned* __restrict__ mxk,
                float* __restrict__ acc_tot, float* __restrict__ acc1, int N) {
    __shared__ float2 buf[CHUNK];
    const int c = blockIdx.x;
    const int k = blockIdx.y;
    const int base = k * CHUNK;
    const int cnt = min(CHUNK, N - base);
    for (int i = threadIdx.x; i < cnt; i += blockDim.x) {
        float pv = y[(size_t)(base + i) * NC + c];
        buf[i] = make_float2(pv * TEMP, (float)s[base + i]);
    }
    __syncthreads();
    const float mn = dec_f(mnk[c]);
    const float mx = dec_f(mxk[c]);
    const int wave = threadIdx.x >> 6;
    const int lane = threadIdx.x & 63;
    for (int p = wave; p < NP; p += 4) {
        float frac = (float)p * (1.0f / 99.0f);
        float g = mn + (mx - mn) * frac;
        float gs = g * TEMP;
        float tot = 0.f, s1 = 0.f;
        for (int i = lane; i < cnt; i += 64) {
            float2 v = buf[i];
            float e = __expf(v.x - gs);                    // exp(10*(pred - g))
            float sig = __builtin_amdgcn_rcpf(1.0f + e);   // sigmoid(10*(g - pred))
            tot += sig;
            s1  += sig * v.y;
        }
#pragma unroll
        for (int off = 1; off < 64; off <<= 1) {
            tot += __shfl_xor(tot, off);
            s1  += __shfl_xor(s1, off);
        }
        if (lane == 0) {
            atomicAdd(&acc_tot[c * NP + p], tot);
            atomicAdd(&acc1[c * NP + p], s1);
        }
    }
}

// Kernel 3: delta + global max
__global__ __launch_bounds__(256)
void finalize_kernel(const float* __restrict__ acc_tot, const float* __restrict__ acc1,
                     const int* __restrict__ n1cnt, float* __restrict__ out, int N) {
    int idx = blockIdx.x * blockDim.x + threadIdx.x;
    int n1 = *n1cnt;
    float inv1 = 1.0f / (float)n1;
    float inv0 = 1.0f / (float)(N - n1);
    float d = 0.f;
    if (idx < NC * NP) {
        float t  = acc_tot[idx];
        float s1 = acc1[idx];
        float cdf1 = s1 * inv1;
        float cdf0 = (t - s1) * inv0;
        d = fabsf(cdf0 - cdf1);
    }
#pragma unroll
    for (int off = 1; off < 64; off <<= 1)
        d = fmaxf(d, __shfl_xor(d, off));
    if ((threadIdx.x & 63) == 0)
        atomicMax((int*)out, __float_as_int(d));   // d >= 0, out pre-zeroed
}

extern "C" void kernel_launch(void* const* d_in, const int* in_sizes, int n_in,
                              void* d_out, int out_size, void* d_ws, size_t ws_size,
                              hipStream_t stream) {
    const float* y = (const float*)d_in[0];
    const int* s   = (const int*)d_in[1];
    const int N = in_sizes[1];
    const int nchunk = (N + CHUNK - 1) / CHUNK;

    unsigned char* ws = (unsigned char*)d_ws;
    unsigned* mnk  = (unsigned*)ws;                 // [NC]   offset 0
    unsigned* mxk  = (unsigned*)(ws + 4 * NC);      // [NC]   offset 80
    int* n1cnt     = (int*)(ws + 8 * NC);           //        offset 160
    float* acc_tot = (float*)(ws + 256);            // [NC*NP]
    float* acc1    = (float*)(ws + 256 + 4 * NC * NP);

    // Re-init every call (harness does not re-poison between replays):
    hipMemsetAsync(mnk, 0xFF, 4 * NC, stream);                       // min keys -> max uint
    hipMemsetAsync(mxk, 0, (256 - 4 * NC) + 8 * NC * NP, stream);    // max keys, n1, acc arrays -> 0
    hipMemsetAsync(d_out, 0, sizeof(float), stream);

    minmax_kernel<<<40, 256, 0, stream>>>(y, s, mnk, mxk, n1cnt, N);

    dim3 gridB(NC, nchunk);
    cdf_kernel<<<gridB, 256, 0, stream>>>(y, s, mnk, mxk, acc_tot, acc1, N);

    finalize_kernel<<<(NC * NP + 255) / 256, 256, 0, stream>>>(acc_tot, acc1, n1cnt,
                                                               (float*)d_out, N);
}

// Round 2
// 63.755 us; speedup vs baseline: 1.8100x; 1.8100x over previous
//
#include <hip/hip_runtime.h>

#define NC 20            // classes (fixed by problem)
#define NP 100           // probes
#define PG 10            // probes per block in cdf kernel
#define NPG (NP / PG)    // 10 probe-groups
#define SLICES 4         // n-slices per (class, probe-group)
#define KLOG2E 14.426950408889634f   // TEMPERATURE * log2(e)
#define PADV 1e38f       // pad value: exp2(huge)=inf -> rcp(inf)=0 -> inert

__device__ __forceinline__ float fexp2(float x) {
#if __has_builtin(__builtin_amdgcn_exp2f)
    return __builtin_amdgcn_exp2f(x);
#else
    return __builtin_exp2f(x);
#endif
}

// Order-preserving float <-> uint key (for atomic min/max on floats)
__device__ __forceinline__ unsigned enc_f(float f) {
    unsigned u = __float_as_uint(f);
    return (u & 0x80000000u) ? ~u : (u | 0x80000000u);
}
__device__ __forceinline__ float dec_f(unsigned k) {
    unsigned u = (k & 0x80000000u) ? (k & 0x7fffffffu) : ~k;
    return __uint_as_float(u);
}
__device__ __forceinline__ float sgpr_f(float x) {
    return __uint_as_float(__builtin_amdgcn_readfirstlane(__float_as_uint(x)));
}

// Kernel A: fused transpose+scale (yS[c][n] = y[n][c]*K, padded with PADV),
// sf[n] = (float)s[n], per-class min/max (block-aggregated atomics), n1 count.
template<bool WRITE_T>
__global__ __launch_bounds__(256)
void prep_kernel(const float* __restrict__ y, const int* __restrict__ s,
                 float* __restrict__ yS, float* __restrict__ sf,
                 unsigned* __restrict__ mnk, unsigned* __restrict__ mxk,
                 int* __restrict__ n1cnt, int N, int ncap) {
    __shared__ float smn[4][NC], smx[4][NC];
    __shared__ int scnt[4];
    float mn[NC], mx[NC];
#pragma unroll
    for (int c = 0; c < NC; ++c) { mn[c] = 3.4e38f; mx[c] = -3.4e38f; }
    int cnt = 0;
    int stride = gridDim.x * blockDim.x;
    for (int n = blockIdx.x * blockDim.x + threadIdx.x; n < ncap; n += stride) {
        if (n < N) {
            const float4* row = (const float4*)(y + (size_t)n * NC);
            float v[NC];
#pragma unroll
            for (int q = 0; q < NC / 4; ++q) {
                float4 f = row[q];
                v[4*q+0] = f.x; v[4*q+1] = f.y; v[4*q+2] = f.z; v[4*q+3] = f.w;
            }
            int m = s[n];
#pragma unroll
            for (int c = 0; c < NC; ++c) {
                mn[c] = fminf(mn[c], v[c]);
                mx[c] = fmaxf(mx[c], v[c]);
                if (WRITE_T) yS[(size_t)c * ncap + n] = v[c] * KLOG2E;
            }
            if (WRITE_T) sf[n] = (float)m;
            cnt += m;
        } else if (WRITE_T) {
#pragma unroll
            for (int c = 0; c < NC; ++c) yS[(size_t)c * ncap + n] = PADV;
            sf[n] = 0.f;
        }
    }
    // wave-level butterfly reduce
#pragma unroll
    for (int off = 1; off < 64; off <<= 1) {
#pragma unroll
        for (int c = 0; c < NC; ++c) {
            mn[c] = fminf(mn[c], __shfl_xor(mn[c], off));
            mx[c] = fmaxf(mx[c], __shfl_xor(mx[c], off));
        }
        cnt += __shfl_xor(cnt, off);
    }
    const int wave = threadIdx.x >> 6, lane = threadIdx.x & 63;
    if (lane == 0) {
#pragma unroll
        for (int c = 0; c < NC; ++c) { smn[wave][c] = mn[c]; smx[wave][c] = mx[c]; }
        scnt[wave] = cnt;
    }
    __syncthreads();
    const int t = threadIdx.x;
    if (t < NC) {
        float v = fminf(fminf(smn[0][t], smn[1][t]), fminf(smn[2][t], smn[3][t]));
        atomicMin(&mnk[t], enc_f(v));
    } else if (t < 2 * NC) {
        int c = t - NC;
        float v = fmaxf(fmaxf(smx[0][c], smx[1][c]), fmaxf(smx[2][c], smx[3][c]));
        atomicMax(&mxk[c], enc_f(v));
    } else if (t == 2 * NC) {
        atomicAdd(n1cnt, scnt[0] + scnt[1] + scnt[2] + scnt[3]);
    }
}

// Kernel B: block = (class c, probe-group pg, slice). Register-resident:
// each thread streams float4 of pre-scaled preds + masks, evaluates PG probes.
template<bool RAW>
__global__ __launch_bounds__(256)
void cdf2_kernel(const float* __restrict__ yS, const float* __restrict__ sf,
                 const float* __restrict__ y, const int* __restrict__ s,
                 const unsigned* __restrict__ mnk, const unsigned* __restrict__ mxk,
                 float* __restrict__ acc_tot, float* __restrict__ acc1,
                 int N, int ncap) {
    const int c = blockIdx.x;
    const int pg = blockIdx.y;
    const float mn = dec_f(mnk[c]);
    const float mx = dec_f(mxk[c]);
    float gs[PG];
#pragma unroll
    for (int j = 0; j < PG; ++j) {
        int p = pg * PG + j;
        float frac = (float)p / 99.0f;              // p / (NUM_PROBES-1), true divide
        float g = mn + (mx - mn) * frac;
        gs[j] = sgpr_f(g * KLOG2E);
    }
    float tot[PG], s1[PG];
#pragma unroll
    for (int j = 0; j < PG; ++j) { tot[j] = 0.f; s1[j] = 0.f; }

    const int nq = ncap >> 2;
    if (!RAW) {
        const float4* yv4 = (const float4*)(yS + (size_t)c * ncap);
        const float4* sv4 = (const float4*)sf;
        for (int q = blockIdx.z * 256 + threadIdx.x; q < nq; q += 256 * SLICES) {
            float4 yv = yv4[q];
            float4 mv = sv4[q];
            float ye[4] = {yv.x, yv.y, yv.z, yv.w};
            float me[4] = {mv.x, mv.y, mv.z, mv.w};
#pragma unroll
            for (int e = 0; e < 4; ++e) {
#pragma unroll
                for (int j = 0; j < PG; ++j) {
                    float ex = fexp2(ye[e] - gs[j]);             // 2^(K*(pred-g))
                    float sg = __builtin_amdgcn_rcpf(1.0f + ex); // sigmoid(T*(g-pred))
                    tot[j] += sg;
                    s1[j] = fmaf(sg, me[e], s1[j]);
                }
            }
        }
    } else {
        for (int q = blockIdx.z * 256 + threadIdx.x; q < nq; q += 256 * SLICES) {
#pragma unroll
            for (int e = 0; e < 4; ++e) {
                int n = q * 4 + e;
                bool valid = n < N;
                float ye = valid ? y[(size_t)n * NC + c] * KLOG2E : PADV;
                float me = valid ? (float)s[n] : 0.f;
#pragma unroll
                for (int j = 0; j < PG; ++j) {
                    float ex = fexp2(ye - gs[j]);
                    float sg = __builtin_amdgcn_rcpf(1.0f + ex);
                    tot[j] += sg;
                    s1[j] = fmaf(sg, me, s1[j]);
                }
            }
        }
    }
    // wave butterfly reduce, one atomicAdd pair per probe per wave
#pragma unroll
    for (int off = 1; off < 64; off <<= 1) {
#pragma unroll
        for (int j = 0; j < PG; ++j) {
            tot[j] += __shfl_xor(tot[j], off);
            s1[j]  += __shfl_xor(s1[j], off);
        }
    }
    if ((threadIdx.x & 63) == 0) {
#pragma unroll
        for (int j = 0; j < PG; ++j) {
            int p = pg * PG + j;
            atomicAdd(&acc_tot[c * NP + p], tot[j]);
            atomicAdd(&acc1[c * NP + p], s1[j]);
        }
    }
}

// Kernel C: delta + global max
__global__ __launch_bounds__(256)
void finalize_kernel(const float* __restrict__ acc_tot, const float* __restrict__ acc1,
                     const int* __restrict__ n1cnt, float* __restrict__ out, int N) {
    int idx = blockIdx.x * blockDim.x + threadIdx.x;
    int n1 = *n1cnt;
    float inv1 = 1.0f / (float)n1;
    float inv0 = 1.0f / (float)(N - n1);
    float d = 0.f;
    if (idx < NC * NP) {
        float t  = acc_tot[idx];
        float s1 = acc1[idx];
        d = fabsf((t - s1) * inv0 - s1 * inv1);
    }
#pragma unroll
    for (int off = 1; off < 64; off <<= 1)
        d = fmaxf(d, __shfl_xor(d, off));
    if ((threadIdx.x & 63) == 0)
        atomicMax((int*)out, __float_as_int(d));   // d >= 0, out pre-zeroed
}

extern "C" void kernel_launch(void* const* d_in, const int* in_sizes, int n_in,
                              void* d_out, int out_size, void* d_ws, size_t ws_size,
                              hipStream_t stream) {
    const float* y = (const float*)d_in[0];
    const int* s   = (const int*)d_in[1];
    const int N = in_sizes[1];
    const int ncap = ((N + 1023) / 1024) * 1024;

    unsigned char* ws = (unsigned char*)d_ws;
    unsigned* mnk  = (unsigned*)ws;            // [NC]      @0
    unsigned* mxk  = (unsigned*)(ws + 128);    // [NC]      @128
    int* n1cnt     = (int*)(ws + 208);         //           @208
    float* acc_tot = (float*)(ws + 256);       // [NC*NP]   @256
    float* acc1    = (float*)(ws + 256 + 4 * NC * NP);
    float* yS      = (float*)(ws + 16384);                       // [NC][ncap]
    float* sf      = (float*)(ws + 16384 + (size_t)4 * NC * ncap); // [ncap]
    size_t need = 16384 + (size_t)4 * NC * ncap + (size_t)4 * ncap;
    bool fat = ws_size >= need;

    // Re-init every call (harness does not re-poison between replays):
    hipMemsetAsync(mnk, 0xFF, 4 * NC, stream);                 // min keys -> max uint
    hipMemsetAsync(ws + 128, 0, 128 + 8 * NC * NP, stream);    // max keys, n1, accs
    hipMemsetAsync(d_out, 0, sizeof(float), stream);

    int gridA = ncap / 256;
    if (fat) prep_kernel<true ><<<gridA, 256, 0, stream>>>(y, s, yS, sf, mnk, mxk, n1cnt, N, ncap);
    else     prep_kernel<false><<<gridA, 256, 0, stream>>>(y, s, nullptr, nullptr, mnk, mxk, n1cnt, N, ncap);

    dim3 gB(NC, NPG, SLICES);
    if (fat) cdf2_kernel<false><<<gB, 256, 0, stream>>>(yS, sf, y, s, mnk, mxk, acc_tot, acc1, N, ncap);
    else     cdf2_kernel<true ><<<gB, 256, 0, stream>>>(nullptr, nullptr, y, s, mnk, mxk, acc_tot, acc1, N, ncap);

    finalize_kernel<<<(NC * NP + 255) / 256, 256, 0, stream>>>(acc_tot, acc1, n1cnt,
                                                               (float*)d_out, N);
}

// Round 3
// 53.262 us; speedup vs baseline: 2.1666x; 1.1970x over previous
//
#include <hip/hip_runtime.h>

#define NC 20            // classes (fixed by problem)
#define NP 100           // probes
#define PG 10            // probes per block in cdf kernel
#define NPG (NP / PG)    // 10 probe-groups
#define SLICES 10        // n-slices -> grid 20*10*10 = 2000 blocks (co-resident)
#define TPB 256
#define KLOG2E 14.426950408889634f   // TEMPERATURE * log2(e)

__device__ __forceinline__ float fexp2(float x) {
#if __has_builtin(__builtin_amdgcn_exp2f)
    return __builtin_amdgcn_exp2f(x);
#else
    return __builtin_exp2f(x);
#endif
}

// Order-preserving float <-> uint key (for atomic min/max on floats)
__device__ __forceinline__ unsigned enc_f(float f) {
    unsigned u = __float_as_uint(f);
    return (u & 0x80000000u) ? ~u : (u | 0x80000000u);
}
__device__ __forceinline__ float dec_f(unsigned k) {
    unsigned u = (k & 0x80000000u) ? (k & 0x7fffffffu) : ~k;
    return __uint_as_float(u);
}
__device__ __forceinline__ float sgpr_f(float x) {
    return __uint_as_float(__builtin_amdgcn_readfirstlane(__float_as_uint(x)));
}

// Kernel A (prep): per-class raw min/max + n1 count; writes E[c][n] = 2^(K*pred)
// (transposed, padded with +inf) and sf[n] = (float)s[n] (pads = 0).
template<bool WRITE_T>
__global__ __launch_bounds__(256)
void prep_kernel(const float* __restrict__ y, const int* __restrict__ s,
                 float* __restrict__ E, float* __restrict__ sf,
                 unsigned* __restrict__ mnk, unsigned* __restrict__ mxk,
                 int* __restrict__ n1cnt, int N, int ncap) {
    __shared__ float smn[4][NC], smx[4][NC];
    __shared__ int scnt[4];
    float mn[NC], mx[NC];
#pragma unroll
    for (int c = 0; c < NC; ++c) { mn[c] = 3.4e38f; mx[c] = -3.4e38f; }
    int cnt = 0;
    int stride = gridDim.x * blockDim.x;
    for (int n = blockIdx.x * blockDim.x + threadIdx.x; n < ncap; n += stride) {
        bool valid = n < N;
        float v[NC];
        int m = 0;
        if (valid) {
            const float4* row = (const float4*)(y + (size_t)n * NC);
#pragma unroll
            for (int q = 0; q < NC / 4; ++q) {
                float4 f = row[q];
                v[4*q+0] = f.x; v[4*q+1] = f.y; v[4*q+2] = f.z; v[4*q+3] = f.w;
            }
            m = s[n];
#pragma unroll
            for (int c = 0; c < NC; ++c) {
                mn[c] = fminf(mn[c], v[c]);
                mx[c] = fmaxf(mx[c], v[c]);
            }
            cnt += m;
        } else {
#pragma unroll
            for (int c = 0; c < NC; ++c) v[c] = 3.0e38f;   // exp2 -> +inf (inert)
        }
        if (WRITE_T) {
#pragma unroll
            for (int c = 0; c < NC; ++c)
                E[(size_t)c * ncap + n] = fexp2(v[c] * KLOG2E);
            sf[n] = (float)m;   // 0 for pads
        }
    }
    // wave-level butterfly reduce
#pragma unroll
    for (int off = 1; off < 64; off <<= 1) {
#pragma unroll
        for (int c = 0; c < NC; ++c) {
            mn[c] = fminf(mn[c], __shfl_xor(mn[c], off));
            mx[c] = fmaxf(mx[c], __shfl_xor(mx[c], off));
        }
        cnt += __shfl_xor(cnt, off);
    }
    const int wave = threadIdx.x >> 6, lane = threadIdx.x & 63;
    if (lane == 0) {
#pragma unroll
        for (int c = 0; c < NC; ++c) { smn[wave][c] = mn[c]; smx[wave][c] = mx[c]; }
        scnt[wave] = cnt;
    }
    __syncthreads();
    const int t = threadIdx.x;
    if (t < NC) {
        float v = fminf(fminf(smn[0][t], smn[1][t]), fminf(smn[2][t], smn[3][t]));
        atomicMin(&mnk[t], enc_f(v));
    } else if (t < 2 * NC) {
        int c = t - NC;
        float v = fmaxf(fmaxf(smx[0][c], smx[1][c]), fmaxf(smx[2][c], smx[3][c]));
        atomicMax(&mxk[c], enc_f(v));
    } else if (t == 2 * NC) {
        atomicAdd(n1cnt, scnt[0] + scnt[1] + scnt[2] + scnt[3]);
    }
}

// Kernel B (cdf2): block = (class c, probe-group pg, slice z).
// Inner loop per elem-probe: t=fma(E,G,1); r=rcp(t); d=fma(r,w,d).  (1 trans + 2 main)
template<bool RAW>
__global__ __launch_bounds__(256)
void cdf2_kernel(const float* __restrict__ E, const float* __restrict__ sf,
                 const float* __restrict__ y, const int* __restrict__ s,
                 const unsigned* __restrict__ mnk, const unsigned* __restrict__ mxk,
                 const int* __restrict__ n1p,
                 float* __restrict__ acc_d, int N, int ncap) {
    const int c = blockIdx.x;
    const int pg = blockIdx.y;
    const float mn = dec_f(mnk[c]);
    const float mx = dec_f(mxk[c]);
    const int n1 = *n1p;
    const float inv1 = 1.0f / (float)n1;
    const float inv0 = 1.0f / (float)(N - n1);
    const float sA = sgpr_f(inv1 + inv0);   // w = m*sA + sB
    const float sB = sgpr_f(-inv0);

    // G_j = 2^(-K*g_j), wave-parallel: lane j computes probe pg*PG+j
    const int lane = threadIdx.x & 63;
    int p = pg * PG + (lane % PG);
    float frac = (float)p / 99.0f;                  // matches reference fp32 divide
    float g = fmaf(mx - mn, frac, mn);
    float Gl = fexp2(-g * KLOG2E);
    float G[PG];
#pragma unroll
    for (int j = 0; j < PG; ++j) G[j] = sgpr_f(__shfl(Gl, j));

    float d[PG];
#pragma unroll
    for (int j = 0; j < PG; ++j) d[j] = 0.f;

    const int nq = ncap >> 2;
    if (!RAW) {
        const float4* E4 = (const float4*)(E + (size_t)c * ncap);
        const float4* S4 = (const float4*)sf;
        for (int q = blockIdx.z * TPB + threadIdx.x; q < nq; q += TPB * SLICES) {
            float4 ev = E4[q];
            float4 mv = S4[q];
            float ee[4] = {ev.x, ev.y, ev.z, ev.w};
            float ww[4];
            ww[0] = fmaf(mv.x, sA, sB); ww[1] = fmaf(mv.y, sA, sB);
            ww[2] = fmaf(mv.z, sA, sB); ww[3] = fmaf(mv.w, sA, sB);
#pragma unroll
            for (int e = 0; e < 4; ++e) {
#pragma unroll
                for (int j = 0; j < PG; ++j) {
                    float t = fmaf(ee[e], G[j], 1.0f);   // 1 + E*G  (inf-safe)
                    float r = __builtin_amdgcn_rcpf(t);  // sigmoid
                    d[j] = fmaf(r, ww[e], d[j]);
                }
            }
        }
    } else {
        for (int q = blockIdx.z * TPB + threadIdx.x; q < nq; q += TPB * SLICES) {
#pragma unroll
            for (int e = 0; e < 4; ++e) {
                int n = q * 4 + e;
                bool valid = n < N;
                float ev = valid ? fexp2(y[(size_t)n * NC + c] * KLOG2E)
                                 : __builtin_inff();
                float w  = valid ? fmaf((float)s[n], sA, sB) : 0.f;
#pragma unroll
                for (int j = 0; j < PG; ++j) {
                    float t = fmaf(ev, G[j], 1.0f);
                    float r = __builtin_amdgcn_rcpf(t);
                    d[j] = fmaf(r, w, d[j]);
                }
            }
        }
    }
    // wave butterfly reduce, one atomicAdd per probe per wave
#pragma unroll
    for (int off = 1; off < 64; off <<= 1) {
#pragma unroll
        for (int j = 0; j < PG; ++j) d[j] += __shfl_xor(d[j], off);
    }
    if (lane == 0) {
#pragma unroll
        for (int j = 0; j < PG; ++j)
            atomicAdd(&acc_d[c * NP + pg * PG + j], d[j]);
    }
}

// Kernel C: single block, |d| max over all (c,p), direct store (no pre-zero of out)
__global__ __launch_bounds__(256)
void finalize_kernel(const float* __restrict__ acc_d, float* __restrict__ out) {
    __shared__ float red[4];
    float m = 0.f;
    for (int i = threadIdx.x; i < NC * NP; i += 256)
        m = fmaxf(m, fabsf(acc_d[i]));
#pragma unroll
    for (int off = 1; off < 64; off <<= 1)
        m = fmaxf(m, __shfl_xor(m, off));
    const int wave = threadIdx.x >> 6, lane = threadIdx.x & 63;
    if (lane == 0) red[wave] = m;
    __syncthreads();
    if (threadIdx.x == 0)
        out[0] = fmaxf(fmaxf(red[0], red[1]), fmaxf(red[2], red[3]));
}

extern "C" void kernel_launch(void* const* d_in, const int* in_sizes, int n_in,
                              void* d_out, int out_size, void* d_ws, size_t ws_size,
                              hipStream_t stream) {
    const float* y = (const float*)d_in[0];
    const int* s   = (const int*)d_in[1];
    const int N = in_sizes[1];
    const int ncap = ((N + 1023) / 1024) * 1024;

    unsigned char* ws = (unsigned char*)d_ws;
    unsigned* mnk = (unsigned*)ws;             // [NC]      @0    (0xFF fill)
    unsigned* mxk = (unsigned*)(ws + 128);     // [NC]      @128  (zeros)
    int* n1cnt    = (int*)(ws + 208);          //           @208  (zeros)
    float* acc_d  = (float*)(ws + 256);        // [NC*NP]   @256  (zeros)
    float* E      = (float*)(ws + 16384);                          // [NC][ncap]
    float* sf     = (float*)(ws + 16384 + (size_t)4 * NC * ncap);  // [ncap]
    size_t need = 16384 + (size_t)4 * NC * ncap + (size_t)4 * ncap;
    bool fat = ws_size >= need;

    // Re-init every call (harness does not re-poison between replays):
    hipMemsetAsync(mnk, 0xFF, 4 * NC, stream);             // min keys -> max uint
    hipMemsetAsync(ws + 128, 0, 128 + 4 * NC * NP, stream);// max keys, n1, acc_d

    int gridA = ncap / 256;
    if (fat) prep_kernel<true ><<<gridA, 256, 0, stream>>>(y, s, E, sf, mnk, mxk, n1cnt, N, ncap);
    else     prep_kernel<false><<<gridA, 256, 0, stream>>>(y, s, nullptr, nullptr, mnk, mxk, n1cnt, N, ncap);

    dim3 gB(NC, NPG, SLICES);
    if (fat) cdf2_kernel<false><<<gB, 256, 0, stream>>>(E, sf, y, s, mnk, mxk, n1cnt, acc_d, N, ncap);
    else     cdf2_kernel<true ><<<gB, 256, 0, stream>>>(nullptr, nullptr, y, s, mnk, mxk, n1cnt, acc_d, N, ncap);

    finalize_kernel<<<1, 256, 0, stream>>>(acc_d, (float*)d_out);
}

// Round 4
// 33.183 us; speedup vs baseline: 3.4776x; 1.6051x over previous
//
#include <hip/hip_runtime.h>

#define NC 20            // classes (fixed by problem)
#define NP 100           // probes
#define PG 10            // probes per cdf block
#define NPG (NP / PG)    // 10 probe-groups
#define SLICES 8         // n-slices -> grid 20*10*8 = 1600 blocks
#define TPB 256
#define KLOG2E 14.426950408889634f   // TEMPERATURE * log2(e)
#define NBS 256          // partial-array stride (max prep blocks.x)

__device__ __forceinline__ float fexp2(float x) {
#if __has_builtin(__builtin_amdgcn_exp2f)
    return __builtin_amdgcn_exp2f(x);
#else
    return __builtin_exp2f(x);
#endif
}
__device__ __forceinline__ float sgpr_f(float x) {
    return __uint_as_float(__builtin_amdgcn_readfirstlane(__float_as_uint(x)));
}

// Kernel A (prep): grid (nb, 5). Block covers 256 rows x 4 classes (q = class quad).
// Writes E[c][n] = 2^(K*pred) (padded with +inf), sf[n] = (float)s[n] (pads 0),
// and PER-BLOCK partial min/max/count to unique slots (no atomics, no init).
template<bool WRITE_T>
__global__ __launch_bounds__(256)
void prep_kernel(const float* __restrict__ y, const int* __restrict__ s,
                 float* __restrict__ E, float* __restrict__ sf,
                 float* __restrict__ part_mn, float* __restrict__ part_mx,
                 int* __restrict__ part_cnt, int N, int ncap) {
    const int q = blockIdx.y;          // classes 4q .. 4q+3
    const int bx = blockIdx.x;
    float mn[4] = {3.4e38f, 3.4e38f, 3.4e38f, 3.4e38f};
    float mx[4] = {-3.4e38f, -3.4e38f, -3.4e38f, -3.4e38f};
    int cnt = 0;
    const int stride = gridDim.x * 256;
    for (int n = bx * 256 + threadIdx.x; n < ncap; n += stride) {
        if (n < N) {
            float4 f = ((const float4*)y)[n * 5 + q];   // y[n][4q..4q+3]
            float v[4] = {f.x, f.y, f.z, f.w};
#pragma unroll
            for (int cc = 0; cc < 4; ++cc) {
                mn[cc] = fminf(mn[cc], v[cc]);
                mx[cc] = fmaxf(mx[cc], v[cc]);
                if (WRITE_T) E[(size_t)(4 * q + cc) * ncap + n] = fexp2(v[cc] * KLOG2E);
            }
            if (q == 0) {
                int m = s[n];
                cnt += m;
                if (WRITE_T) sf[n] = (float)m;
            }
        } else if (WRITE_T) {
#pragma unroll
            for (int cc = 0; cc < 4; ++cc)
                E[(size_t)(4 * q + cc) * ncap + n] = __builtin_inff();  // inert pad
            if (q == 0) sf[n] = 0.f;
        }
    }
    // wave butterfly
#pragma unroll
    for (int off = 1; off < 64; off <<= 1) {
#pragma unroll
        for (int cc = 0; cc < 4; ++cc) {
            mn[cc] = fminf(mn[cc], __shfl_xor(mn[cc], off));
            mx[cc] = fmaxf(mx[cc], __shfl_xor(mx[cc], off));
        }
        cnt += __shfl_xor(cnt, off);
    }
    __shared__ float smn[4][4], smx[4][4];
    __shared__ int scnt[4];
    const int wave = threadIdx.x >> 6, lane = threadIdx.x & 63;
    if (lane == 0) {
#pragma unroll
        for (int cc = 0; cc < 4; ++cc) { smn[wave][cc] = mn[cc]; smx[wave][cc] = mx[cc]; }
        scnt[wave] = cnt;
    }
    __syncthreads();
    const int t = threadIdx.x;
    if (t < 4) {
        part_mn[(4 * q + t) * NBS + bx] =
            fminf(fminf(smn[0][t], smn[1][t]), fminf(smn[2][t], smn[3][t]));
    } else if (t < 8) {
        int cc = t - 4;
        part_mx[(4 * q + cc) * NBS + bx] =
            fmaxf(fmaxf(smx[0][cc], smx[1][cc]), fmaxf(smx[2][cc], smx[3][cc]));
    } else if (t == 8 && q == 0) {
        part_cnt[bx] = scnt[0] + scnt[1] + scnt[2] + scnt[3];
    }
}

// Kernel B (cdf2): block = (class c, probe-group pg, slice z).
// Stage-2 partial reduce (min/max/n1), then: t=fma(E,G,1); r=rcp(t); d=fma(r,w,d).
template<bool RAW>
__global__ __launch_bounds__(256)
void cdf2_kernel(const float* __restrict__ E, const float* __restrict__ sf,
                 const float* __restrict__ y, const int* __restrict__ s,
                 const float* __restrict__ part_mn, const float* __restrict__ part_mx,
                 const int* __restrict__ part_cnt,
                 float* __restrict__ acc_part, int N, int ncap, int nb) {
    const int c = blockIdx.x;
    const int pg = blockIdx.y;
    // stage-2 reduce of prep partials for this class + n1 count
    float lmn = 3.4e38f, lmx = -3.4e38f;
    int lcnt = 0;
    for (int t = threadIdx.x; t < nb; t += 256) {
        lmn = fminf(lmn, part_mn[c * NBS + t]);
        lmx = fmaxf(lmx, part_mx[c * NBS + t]);
        lcnt += part_cnt[t];
    }
#pragma unroll
    for (int off = 1; off < 64; off <<= 1) {
        lmn = fminf(lmn, __shfl_xor(lmn, off));
        lmx = fmaxf(lmx, __shfl_xor(lmx, off));
        lcnt += __shfl_xor(lcnt, off);
    }
    __shared__ float rmn[4], rmx[4];
    __shared__ int rcnt[4];
    const int wave = threadIdx.x >> 6, lane = threadIdx.x & 63;
    if (lane == 0) { rmn[wave] = lmn; rmx[wave] = lmx; rcnt[wave] = lcnt; }
    __syncthreads();
    const float mn = fminf(fminf(rmn[0], rmn[1]), fminf(rmn[2], rmn[3]));
    const float mx = fmaxf(fmaxf(rmx[0], rmx[1]), fmaxf(rmx[2], rmx[3]));
    const int n1 = rcnt[0] + rcnt[1] + rcnt[2] + rcnt[3];
    const float inv1 = 1.0f / (float)n1;
    const float inv0 = 1.0f / (float)(N - n1);
    const float sA = sgpr_f(inv1 + inv0);   // w = m*sA + sB
    const float sB = sgpr_f(-inv0);

    // G_j = 2^(-K*g_j): lane j computes probe pg*PG+j, broadcast to SGPRs
    int p = pg * PG + (lane % PG);
    float frac = (float)p / 99.0f;                  // matches reference fp32 divide
    float g = fmaf(mx - mn, frac, mn);
    float Gl = fexp2(-g * KLOG2E);
    float G[PG];
#pragma unroll
    for (int j = 0; j < PG; ++j) G[j] = sgpr_f(__shfl(Gl, j));

    float d[PG];
#pragma unroll
    for (int j = 0; j < PG; ++j) d[j] = 0.f;

    const int nq = ncap >> 2;
    if (!RAW) {
        const float4* E4 = (const float4*)(E + (size_t)c * ncap);
        const float4* S4 = (const float4*)sf;
        for (int q = blockIdx.z * TPB + threadIdx.x; q < nq; q += TPB * SLICES) {
            float4 ev = E4[q];
            float4 mv = S4[q];
            float ee[4] = {ev.x, ev.y, ev.z, ev.w};
            float ww[4];
            ww[0] = fmaf(mv.x, sA, sB); ww[1] = fmaf(mv.y, sA, sB);
            ww[2] = fmaf(mv.z, sA, sB); ww[3] = fmaf(mv.w, sA, sB);
#pragma unroll
            for (int e = 0; e < 4; ++e) {
#pragma unroll
                for (int j = 0; j < PG; ++j) {
                    float t = fmaf(ee[e], G[j], 1.0f);   // 1 + E*G (inf-safe)
                    float r = __builtin_amdgcn_rcpf(t);  // sigmoid
                    d[j] = fmaf(r, ww[e], d[j]);
                }
            }
        }
    } else {
        for (int q = blockIdx.z * TPB + threadIdx.x; q < nq; q += TPB * SLICES) {
#pragma unroll
            for (int e = 0; e < 4; ++e) {
                int n = q * 4 + e;
                bool valid = n < N;
                float ev = valid ? fexp2(y[(size_t)n * NC + c] * KLOG2E)
                                 : __builtin_inff();
                float w  = valid ? fmaf((float)s[n], sA, sB) : 0.f;
#pragma unroll
                for (int j = 0; j < PG; ++j) {
                    float t = fmaf(ev, G[j], 1.0f);
                    float r = __builtin_amdgcn_rcpf(t);
                    d[j] = fmaf(r, w, d[j]);
                }
            }
        }
    }
    // block reduce: wave butterfly -> LDS -> unique slot write (no atomics)
#pragma unroll
    for (int off = 1; off < 64; off <<= 1) {
#pragma unroll
        for (int j = 0; j < PG; ++j) d[j] += __shfl_xor(d[j], off);
    }
    __shared__ float sd[4][PG];
    if (lane == 0) {
#pragma unroll
        for (int j = 0; j < PG; ++j) sd[wave][j] = d[j];
    }
    __syncthreads();
    if (threadIdx.x < PG) {
        int j = threadIdx.x;
        float v = (sd[0][j] + sd[1][j]) + (sd[2][j] + sd[3][j]);
        acc_part[(size_t)(c * NP + pg * PG + j) * SLICES + blockIdx.z] = v;
    }
}

// Kernel C: single block; sum z-slices, |.|, global max, direct store.
__global__ __launch_bounds__(256)
void finalize_kernel(const float* __restrict__ acc_part, float* __restrict__ out) {
    float m = 0.f;
    for (int i = threadIdx.x; i < NC * NP; i += 256) {
        const float4* p4 = (const float4*)(acc_part + (size_t)i * SLICES);
        float4 a = p4[0], b = p4[1];
        float ssum = ((a.x + a.y) + (a.z + a.w)) + ((b.x + b.y) + (b.z + b.w));
        m = fmaxf(m, fabsf(ssum));
    }
#pragma unroll
    for (int off = 1; off < 64; off <<= 1)
        m = fmaxf(m, __shfl_xor(m, off));
    __shared__ float red[4];
    const int wave = threadIdx.x >> 6, lane = threadIdx.x & 63;
    if (lane == 0) red[wave] = m;
    __syncthreads();
    if (threadIdx.x == 0)
        out[0] = fmaxf(fmaxf(red[0], red[1]), fmaxf(red[2], red[3]));
}

extern "C" void kernel_launch(void* const* d_in, const int* in_sizes, int n_in,
                              void* d_out, int out_size, void* d_ws, size_t ws_size,
                              hipStream_t stream) {
    const float* y = (const float*)d_in[0];
    const int* s   = (const int*)d_in[1];
    const int N = in_sizes[1];
    const int ncap = ((N + 1023) / 1024) * 1024;
    int nb = ncap / 256;
    if (nb > NBS) nb = NBS;

    unsigned char* ws = (unsigned char*)d_ws;
    float* part_mn = (float*)ws;                    // [NC][NBS]  @0      (20480 B)
    float* part_mx = (float*)(ws + 20480);          // [NC][NBS]  @20480  (20480 B)
    int*   part_cnt= (int*)  (ws + 40960);          // [NBS]      @40960  (1024 B)
    float* acc_part= (float*)(ws + 45056);          // [NC*NP][SLICES] (64000 B)
    float* E       = (float*)(ws + 131072);                           // [NC][ncap]
    float* sf      = (float*)(ws + 131072 + (size_t)4 * NC * ncap);   // [ncap]
    size_t need = 131072 + (size_t)4 * (NC + 1) * ncap;
    bool fat = ws_size >= need;

    dim3 gA(nb, 5);
    if (fat) prep_kernel<true ><<<gA, 256, 0, stream>>>(y, s, E, sf, part_mn, part_mx, part_cnt, N, ncap);
    else     prep_kernel<false><<<gA, 256, 0, stream>>>(y, s, nullptr, nullptr, part_mn, part_mx, part_cnt, N, ncap);

    dim3 gB(NC, NPG, SLICES);
    if (fat) cdf2_kernel<false><<<gB, 256, 0, stream>>>(E, sf, y, s, part_mn, part_mx, part_cnt, acc_part, N, ncap, nb);
    else     cdf2_kernel<true ><<<gB, 256, 0, stream>>>(nullptr, nullptr, y, s, part_mn, part_mx, part_cnt, acc_part, N, ncap, nb);

    finalize_kernel<<<1, 256, 0, stream>>>(acc_part, (float*)d_out);
}